// Round 13
// baseline (196.871 us; speedup 1.0000x reference)
//
#include <hip/hip_runtime.h>
#include <hip/hip_fp16.h>

namespace {

typedef _Float16 half8 __attribute__((ext_vector_type(8)));
typedef float f32x4 __attribute__((ext_vector_type(4)));
typedef unsigned int u32x4 __attribute__((ext_vector_type(4)));
typedef unsigned int u32x2 __attribute__((ext_vector_type(2)));
typedef int i32x4 __attribute__((ext_vector_type(4)));

constexpr int kN = 65536;
constexpr int kD = 32;
constexpr int kPts = 2 * kN;                 // 131072 points (B*N)
constexpr int kThreads = 256;                // 4 waves
constexpr int kPtsPerBlk = 64;               // 16 points per wave
constexpr int kBlocks = kPts / kPtsPerBlk;   // 2048
constexpr int kNumFrags = 24;
static_assert(kBlocks * kPtsPerBlk == kPts, "grid must tile points exactly");
static_assert(kN % kPtsPerBlk == 0, "blocks must not straddle batch boundary");

__device__ __forceinline__ float relu_(float v) { return fmaxf(v, 0.f); }
__device__ __forceinline__ float lrelu_(float v) { return v >= 0.f ? v : 0.2f * v; }

// ---- non-temporal helpers (evict-first: keep streaming traffic out of the
// L2 set that must hold the 4 MB gather working set) ----
__device__ __forceinline__ u32x4 ntload_u4(const uint4* p) {
    return __builtin_nontemporal_load(reinterpret_cast<const u32x4*>(p));
}
__device__ __forceinline__ void ntstore_u4(uint4* p, u32x4 v) {
    __builtin_nontemporal_store(v, reinterpret_cast<u32x4*>(p));
}
__device__ __forceinline__ f32x4 ntload_f4(const float* p) {
    return __builtin_nontemporal_load(reinterpret_cast<const f32x4*>(p));
}
__device__ __forceinline__ void ntstore_f4(float* p, f32x4 v) {
    __builtin_nontemporal_store(v, reinterpret_cast<f32x4*>(p));
}

// channel permutation induced by the interleaved z-row layout:
// row = 16 half2 slots, slot n holds (ch n, ch n+16).
__device__ __forceinline__ int pi_(int k) {
    const int c = ((k >> 3) << 2) + ((k & 7) >> 1);
    return (k & 1) ? c + 16 : c;
}

// XCD-aware block swizzle: assuming bid->XCD is round-robin (bid & 7),
// XCDs 0-3 take batch 0, XCDs 4-7 take batch 1 (gather set == L2 capacity).
__device__ __forceinline__ int swizzled_pbase(int bid) {
    const int xcd   = bid & 7;
    const int slot  = bid >> 3;                           // 0..255
    const int batch = xcd >> 2;
    const int local = (xcd & 3) * (kBlocks / 8) + slot;   // 0..1023
    return batch * kN + local * kPtsPerBlk;
}

// ---------------------------------------------------------------------------
// zprep: z1 = relu((x @ W2_0) * g2_0 + b2_0) (interleaved fp16), packs idx
// to u16 pairs, and (block 0 only) builds the fp16 B-fragment bank.
// ---------------------------------------------------------------------------
__global__ __launch_bounds__(kThreads, 4)
void zprep_kernel(const float* __restrict__ x, const int4* __restrict__ idx4,
                  const float* __restrict__ W2d, const float* __restrict__ W1d,
                  const float* __restrict__ g2v, const float* __restrict__ b2v,
                  __half2* __restrict__ z, uint2* __restrict__ idx16,
                  uint4* __restrict__ wpack)
{
    const int tid = threadIdx.x;
    if (blockIdx.x == 0) {
        for (int id = tid; id < kNumFrags * 64; id += kThreads) {
            const int fid = id >> 6, l = id & 63, n = l & 15, q = l >> 4;
            half8 v;
            if (fid < 2) {
                const int h = fid;
#pragma unroll
                for (int j = 0; j < 8; ++j)
                    v[j] = (_Float16)W2d[(q * 8 + j) * kD + h * 16 + n];
            } else {
                const int rel = fid - 2;
                const int layer = (rel < 18) ? rel / 6 : 3;
                const int sub   = (rel < 18) ? rel % 6 : rel - 18;
                if (sub < 4) {
                    const int p = sub >> 1, h = sub & 1;
#pragma unroll
                    for (int j = 0; j < 8; ++j)
                        v[j] = (_Float16)W1d[layer * 2048 + (p * 32 + pi_(q * 8 + j)) * kD + h * 16 + n];
                } else {
                    const int h = sub - 4;
#pragma unroll
                    for (int j = 0; j < 8; ++j)
                        v[j] = (_Float16)W2d[(layer + 1) * 1024 + pi_(q * 8 + j) * kD + h * 16 + n];
                }
            }
            wpack[id] = *reinterpret_cast<const uint4*>(&v);
        }
    }
    {
        const int p = blockIdx.x * kPtsPerBlk + (tid >> 2);
        const int part = tid & 3;
        const i32x4 iv = __builtin_nontemporal_load(
            reinterpret_cast<const i32x4*>(&idx4[p * 4 + part]));
        u32x2 o;
        o.x = (unsigned)(iv.x & 0xFFFF) | ((unsigned)iv.y << 16);
        o.y = (unsigned)(iv.z & 0xFFFF) | ((unsigned)iv.w << 16);
        __builtin_nontemporal_store(o, reinterpret_cast<u32x2*>(&idx16[p * 4 + part]));
    }
    const int w    = tid >> 6;
    const int lane = tid & 63;
    const int n    = lane & 15;
    const int q    = lane >> 4;
    const int pbase = blockIdx.x * kPtsPerBlk + w * 16;
    const int point = pbase + n;

    const f32x4 x0 = ntload_f4(x + (point * 8 + q * 2) * 4);
    const f32x4 x1 = ntload_f4(x + (point * 8 + q * 2 + 1) * 4);
    half8 ax;
    ax[0] = (_Float16)x0.x; ax[1] = (_Float16)x0.y;
    ax[2] = (_Float16)x0.z; ax[3] = (_Float16)x0.w;
    ax[4] = (_Float16)x1.x; ax[5] = (_Float16)x1.y;
    ax[6] = (_Float16)x1.z; ax[7] = (_Float16)x1.w;

    half8 b0, b1;
#pragma unroll
    for (int j = 0; j < 8; ++j) {
        b0[j] = (_Float16)W2d[(q * 8 + j) * kD + n];
        b1[j] = (_Float16)W2d[(q * 8 + j) * kD + 16 + n];
    }
    f32x4 a0 = {0.f, 0.f, 0.f, 0.f}, a1 = {0.f, 0.f, 0.f, 0.f};
    a0 = __builtin_amdgcn_mfma_f32_16x16x32_f16(ax, b0, a0, 0, 0, 0);
    a1 = __builtin_amdgcn_mfma_f32_16x16x32_f16(ax, b1, a1, 0, 0, 0);

    const float g20 = g2v[n], g21 = g2v[16 + n];
    const float c20 = b2v[n], c21 = b2v[16 + n];
#pragma unroll
    for (int r = 0; r < 4; ++r) {
        const int pm = pbase + q * 4 + r;      // C/D row m = q*4 + r
        z[pm * 16 + n] = __floats2half2_rn(relu_(fmaf(a0[r], g20, c20)),
                                           relu_(fmaf(a1[r], g21, c21)));
    }
}

// ---------------------------------------------------------------------------
// blk: adjacent-lane gather (cached; the L2-resident working set) -> packed
// fp16 max/sum -> wave-local LDS bounce -> MFMA conv2 -> wave-local fp32
// transpose -> NON-TEMPORAL streaming epilogue -> MFMA z-next -> cached z
// store (seeds next dispatch's L2). XCD-batch swizzle.
// MODE: 0=first, 1=mid(+cur), 2=mid, 3=last.
// ---------------------------------------------------------------------------
template <int MODE>
__global__ __launch_bounds__(kThreads, 4)
void blk_kernel(const uint4* __restrict__ zsrc, const uint4* __restrict__ idx16,
                const uint4* __restrict__ wfrag,
                const float* __restrict__ g1v, const float* __restrict__ b1v,
                const float* __restrict__ g2v, const float* __restrict__ b2v,
                const uint4* __restrict__ prev, uint4* __restrict__ cur,
                float* __restrict__ sacc, __half2* __restrict__ znext)
{
    __shared__ __align__(16) _Float16 gmax[4][16][40];   // 5120 B
    __shared__ __align__(16) _Float16 gmean[4][16][40];  // 5120 B
    __shared__ float2 tb[4][16][17];                     // 8704 B

    const int tid  = threadIdx.x;
    const int w    = tid >> 6;
    const int lane = tid & 63;
    const int n    = lane & 15;
    const int q    = lane >> 4;
    const int blockPbase = swizzled_pbase(blockIdx.x);
    const int pbase = blockPbase + w * 16;
    const int point = pbase + n;
    const int base  = pbase & ~(kN - 1);       // batch offset (wave-uniform)

    // ---- gather phase: lane = 4*gpt + gq (adjacent quads per point) ----
    const int gpt = lane >> 2;
    const int gq  = lane & 3;
    const int gpoint = pbase + gpt;
    const u32x4 iv0 = ntload_u4(&idx16[gpoint * 2 + 0]);  // streaming: nt
    const u32x4 iv1 = ntload_u4(&idx16[gpoint * 2 + 1]);

    // packed fp16 online max/sum (max exact; fp16 sum error ~1e-4 on mean)
    half8 hmx = (half8)(_Float16)0;            // relu output >= 0
    half8 hsm = (half8)(_Float16)0;
#pragma unroll
    for (int k = 0; k < 16; ++k) {
        unsigned word;
        if (k < 8) word = (k & 2) ? ((k & 4) ? iv0.w : iv0.y)
                                  : ((k & 4) ? iv0.z : iv0.x);
        else {
            const int kk = k - 8;
            word = (kk & 2) ? ((kk & 4) ? iv1.w : iv1.y)
                            : ((kk & 4) ? iv1.z : iv1.x);
        }
        const int row = (k & 1) ? (int)(word >> 16) : (int)(word & 0xFFFFu);
        const uint4 u = zsrc[(base + row) * 4 + gq];   // cached: L2 working set
        const half8 hv = *reinterpret_cast<const half8*>(&u);
        hsm += hv;                                     // v_pk_add_f16 x4
#pragma unroll
        for (int c = 0; c < 8; ++c)
            hmx[c] = hmx[c] > hv[c] ? hmx[c] : hv[c];  // v_max_f16
    }
    {
        const half8 hmn = hsm * (_Float16)0.0625;
        *reinterpret_cast<uint4*>(&gmax[w][gpt][gq * 8]) =
            *reinterpret_cast<const uint4*>(&hmx);
        *reinterpret_cast<uint4*>(&gmean[w][gpt][gq * 8]) =
            *reinterpret_cast<const uint4*>(&hmn);
    }
    __builtin_amdgcn_wave_barrier();   // same wave writes & reads; DS wave-ordered

    // ---- A-frag lanes (n = point, q = k-quarter) pick up their fragments
    const half8 amax  = *reinterpret_cast<const half8*>(&gmax[w][n][q * 8]);
    const half8 amean = *reinterpret_cast<const half8*>(&gmean[w][n][q * 8]);

    const uint4 f0 = wfrag[0 * 64 + lane];
    const uint4 f1 = wfrag[1 * 64 + lane];
    const uint4 f2 = wfrag[2 * 64 + lane];
    const uint4 f3 = wfrag[3 * 64 + lane];
    const half8 bA0 = *reinterpret_cast<const half8*>(&f0);
    const half8 bA1 = *reinterpret_cast<const half8*>(&f1);
    const half8 bB0 = *reinterpret_cast<const half8*>(&f2);
    const half8 bB1 = *reinterpret_cast<const half8*>(&f3);

    // ---- conv2 MFMA ----
    f32x4 acc0 = {0.f, 0.f, 0.f, 0.f}, acc1 = {0.f, 0.f, 0.f, 0.f};
    acc0 = __builtin_amdgcn_mfma_f32_16x16x32_f16(amax,  bA0, acc0, 0, 0, 0);
    acc0 = __builtin_amdgcn_mfma_f32_16x16x32_f16(amean, bB0, acc0, 0, 0, 0);
    acc1 = __builtin_amdgcn_mfma_f32_16x16x32_f16(amax,  bA1, acc1, 0, 0, 0);
    acc1 = __builtin_amdgcn_mfma_f32_16x16x32_f16(amean, bB1, acc1, 0, 0, 0);

    const float g10 = g1v[n], g11 = g1v[16 + n];
    const float c10 = b1v[n], c11 = b1v[16 + n];
#pragma unroll
    for (int r = 0; r < 4; ++r) {
        tb[w][q * 4 + r][n] = make_float2(fmaf(acc0[r], g10, c10),
                                          fmaf(acc1[r], g11, c11));
    }
    __builtin_amdgcn_wave_barrier();
    float y8[8];
#pragma unroll
    for (int s = 0; s < 4; ++s) {
        const float2 f = tb[w][n][q * 4 + s];
        y8[2 * s] = f.x; y8[2 * s + 1] = f.y;
    }

    // ---- A-layout epilogue: streaming traffic is NON-TEMPORAL ----
    const int sb0 = point * kD + q * 4;
    const int sb1 = sb0 + 16;
    float t8[8];
    if (MODE == 0) {
        ntstore_f4(sacc + sb0, (f32x4){y8[0], y8[2], y8[4], y8[6]});
        ntstore_f4(sacc + sb1, (f32x4){y8[1], y8[3], y8[5], y8[7]});
        half8 ch;
#pragma unroll
        for (int c = 0; c < 8; ++c) ch[c] = (_Float16)y8[c];
        ntstore_u4(&cur[point * 4 + q], *reinterpret_cast<const u32x4*>(&ch));
#pragma unroll
        for (int c = 0; c < 8; ++c) t8[c] = lrelu_(y8[c]);
    } else if (MODE == 1 || MODE == 2) {
        f32x4 s0 = ntload_f4(sacc + sb0);
        f32x4 s1 = ntload_f4(sacc + sb1);
        s0.x += y8[0]; s0.y += y8[2]; s0.z += y8[4]; s0.w += y8[6];
        s1.x += y8[1]; s1.y += y8[3]; s1.z += y8[5]; s1.w += y8[7];
        ntstore_f4(sacc + sb0, s0);
        ntstore_f4(sacc + sb1, s1);
        const u32x4 pvv = ntload_u4(&prev[point * 4 + q]);
        const uint4 pv = *reinterpret_cast<const uint4*>(&pvv);
        const __half2* ph = reinterpret_cast<const __half2*>(&pv);
#pragma unroll
        for (int c = 0; c < 4; ++c) {
            const float2 f = __half22float2(ph[c]);
            t8[2 * c]     = lrelu_(y8[2 * c] + f.x);
            t8[2 * c + 1] = lrelu_(y8[2 * c + 1] + f.y);
        }
        if (MODE == 1) {
            half8 ch;
#pragma unroll
            for (int c = 0; c < 8; ++c) ch[c] = (_Float16)y8[c];
            ntstore_u4(&cur[point * 4 + q], *reinterpret_cast<const u32x4*>(&ch));
        }
    } else {  // MODE == 3
        const f32x4 s0 = ntload_f4(sacc + sb0);
        const f32x4 s1 = ntload_f4(sacc + sb1);
        ntstore_f4(sacc + sb0,
            (f32x4){lrelu_(s0.x + y8[0]), lrelu_(s0.y + y8[2]),
                    lrelu_(s0.z + y8[4]), lrelu_(s0.w + y8[6])});
        ntstore_f4(sacc + sb1,
            (f32x4){lrelu_(s1.x + y8[1]), lrelu_(s1.y + y8[3]),
                    lrelu_(s1.z + y8[5]), lrelu_(s1.w + y8[7])});
        return;
    }

    // ---- z-next MFMA; CACHED store (next dispatch's gather set) ----
    half8 at;
#pragma unroll
    for (int c = 0; c < 8; ++c) at[c] = (_Float16)t8[c];
    const uint4 f4 = wfrag[4 * 64 + lane];
    const uint4 f5 = wfrag[5 * 64 + lane];
    const half8 bz0 = *reinterpret_cast<const half8*>(&f4);
    const half8 bz1 = *reinterpret_cast<const half8*>(&f5);
    f32x4 az0 = {0.f, 0.f, 0.f, 0.f}, az1 = {0.f, 0.f, 0.f, 0.f};
    az0 = __builtin_amdgcn_mfma_f32_16x16x32_f16(at, bz0, az0, 0, 0, 0);
    az1 = __builtin_amdgcn_mfma_f32_16x16x32_f16(at, bz1, az1, 0, 0, 0);

    const float g20 = g2v[n], g21 = g2v[16 + n];
    const float c20 = b2v[n], c21 = b2v[16 + n];
#pragma unroll
    for (int r = 0; r < 4; ++r) {
        const int pm = pbase + q * 4 + r;
        znext[pm * 16 + n] = __floats2half2_rn(relu_(fmaf(az0[r], g20, c20)),
                                               relu_(fmaf(az1[r], g21, c21)));
    }
}

}  // namespace

extern "C" void kernel_launch(void* const* d_in, const int* in_sizes, int n_in,
                              void* d_out, int out_size, void* d_ws, size_t ws_size,
                              hipStream_t stream)
{
    const float* x   = (const float*)d_in[0];
    const int4*  idx = (const int4*)d_in[1];
    const float* W2d = (const float*)d_in[2];
    const float* g2  = (const float*)d_in[3];
    const float* b2  = (const float*)d_in[4];
    const float* W1d = (const float*)d_in[5];
    const float* g1  = (const float*)d_in[6];
    const float* b1  = (const float*)d_in[7];
    float* out = (float*)d_out;     // doubles as sacc between dispatches
    char*  ws  = (char*)d_ws;

    constexpr size_t kHalfMap = (size_t)kPts * kD * sizeof(__half);  // 8 MB
    __half2* zA = (__half2*)(ws);
    __half2* zB = (__half2*)(ws + kHalfMap);
    uint4*   cA = (uint4*)(ws + 2 * kHalfMap);                 // x1 (fp16, pi order)
    uint4*   cB = (uint4*)(ws + 3 * kHalfMap);                 // x2 (fp16, pi order)
    uint2*   idx16 = (uint2*)(ws + 4 * kHalfMap);              // 4 MB
    uint4*   wpack = (uint4*)(ws + 4 * kHalfMap + (size_t)kPts * 32);  // 24 KB

    const dim3 grid(kBlocks), blk(kThreads);
    zprep_kernel<<<grid, blk, 0, stream>>>(x, idx, W2d, W1d, g2, b2,
                                           zA, idx16, wpack);

    const uint4* i16 = (const uint4*)idx16;
    blk_kernel<0><<<grid, blk, 0, stream>>>((const uint4*)zA, i16,
        wpack + (2 + 0 * 6) * 64, g1, b1, g2 + 1 * kD, b2 + 1 * kD,
        nullptr, cA, out, zB);
    blk_kernel<1><<<grid, blk, 0, stream>>>((const uint4*)zB, i16,
        wpack + (2 + 1 * 6) * 64, g1 + 1 * kD, b1 + 1 * kD, g2 + 2 * kD, b2 + 2 * kD,
        cA, cB, out, zA);
    blk_kernel<2><<<grid, blk, 0, stream>>>((const uint4*)zA, i16,
        wpack + (2 + 2 * 6) * 64, g1 + 2 * kD, b1 + 2 * kD, g2 + 3 * kD, b2 + 3 * kD,
        cB, nullptr, out, zB);
    blk_kernel<3><<<grid, blk, 0, stream>>>((const uint4*)zB, i16,
        wpack + (2 + 3 * 6) * 64, g1 + 3 * kD, b1 + 3 * kD, nullptr, nullptr,
        nullptr, nullptr, out, nullptr);
}

// Round 14
// 173.373 us; speedup vs baseline: 1.1355x; 1.1355x over previous
//
#include <hip/hip_runtime.h>
#include <hip/hip_fp16.h>

namespace {

typedef _Float16 half8 __attribute__((ext_vector_type(8)));
typedef float f32x4 __attribute__((ext_vector_type(4)));

constexpr int kN = 65536;
constexpr int kD = 32;
constexpr int kPts = 2 * kN;                 // 131072 points (B*N)
constexpr int kThreads = 256;                // 4 waves
constexpr int kPtsPerBlk = 64;               // 16 points per wave
constexpr int kBlocks = kPts / kPtsPerBlk;   // 2048
constexpr int kNumFrags = 24;
static_assert(kBlocks * kPtsPerBlk == kPts, "grid must tile points exactly");
static_assert(kN % kPtsPerBlk == 0, "blocks must not straddle batch boundary");

__device__ __forceinline__ float relu_(float v) { return fmaxf(v, 0.f); }
__device__ __forceinline__ float lrelu_(float v) { return v >= 0.f ? v : 0.2f * v; }

// channel permutation induced by the interleaved z-row layout:
// row = 16 half2 slots, slot n holds (ch n, ch n+16).
__device__ __forceinline__ int pi_(int k) {
    const int c = ((k >> 3) << 2) + ((k & 7) >> 1);
    return (k & 1) ? c + 16 : c;
}

// XCD-aware block swizzle: assuming bid->XCD is round-robin (bid & 7),
// XCDs 0-3 take batch 0, XCDs 4-7 take batch 1. Each XCD then gathers only
// from its batch's 4 MB z map == its L2 capacity. Perf heuristic only;
// correctness does not depend on the mapping (G16). [measured R12: -4 us]
__device__ __forceinline__ int swizzled_pbase(int bid) {
    const int xcd   = bid & 7;
    const int slot  = bid >> 3;                           // 0..255
    const int batch = xcd >> 2;
    const int local = (xcd & 3) * (kBlocks / 8) + slot;   // 0..1023
    return batch * kN + local * kPtsPerBlk;
}

// ---------------------------------------------------------------------------
// zprep: z1 = relu((x @ W2_0) * g2_0 + b2_0) (interleaved fp16), packs idx
// to u16 pairs, and (block 0 only) builds the fp16 B-fragment bank.
// ---------------------------------------------------------------------------
__global__ __launch_bounds__(kThreads, 4)
void zprep_kernel(const float* __restrict__ x, const int4* __restrict__ idx4,
                  const float* __restrict__ W2d, const float* __restrict__ W1d,
                  const float* __restrict__ g2v, const float* __restrict__ b2v,
                  __half2* __restrict__ z, uint2* __restrict__ idx16,
                  uint4* __restrict__ wpack)
{
    const int tid = threadIdx.x;
    if (blockIdx.x == 0) {
        for (int id = tid; id < kNumFrags * 64; id += kThreads) {
            const int fid = id >> 6, l = id & 63, n = l & 15, q = l >> 4;
            half8 v;
            if (fid < 2) {
                const int h = fid;
#pragma unroll
                for (int j = 0; j < 8; ++j)
                    v[j] = (_Float16)W2d[(q * 8 + j) * kD + h * 16 + n];
            } else {
                const int rel = fid - 2;
                const int layer = (rel < 18) ? rel / 6 : 3;
                const int sub   = (rel < 18) ? rel % 6 : rel - 18;
                if (sub < 4) {
                    const int p = sub >> 1, h = sub & 1;
#pragma unroll
                    for (int j = 0; j < 8; ++j)
                        v[j] = (_Float16)W1d[layer * 2048 + (p * 32 + pi_(q * 8 + j)) * kD + h * 16 + n];
                } else {
                    const int h = sub - 4;
#pragma unroll
                    for (int j = 0; j < 8; ++j)
                        v[j] = (_Float16)W2d[(layer + 1) * 1024 + pi_(q * 8 + j) * kD + h * 16 + n];
                }
            }
            wpack[id] = *reinterpret_cast<const uint4*>(&v);
        }
    }
    {
        const int p = blockIdx.x * kPtsPerBlk + (tid >> 2);
        const int part = tid & 3;
        const int4 iv = idx4[p * 4 + part];
        uint2 o;
        o.x = (unsigned)(iv.x & 0xFFFF) | ((unsigned)iv.y << 16);
        o.y = (unsigned)(iv.z & 0xFFFF) | ((unsigned)iv.w << 16);
        idx16[p * 4 + part] = o;
    }
    const int w    = tid >> 6;
    const int lane = tid & 63;
    const int n    = lane & 15;
    const int q    = lane >> 4;
    const int pbase = blockIdx.x * kPtsPerBlk + w * 16;
    const int point = pbase + n;

    const float4 x0 = reinterpret_cast<const float4*>(x)[point * 8 + q * 2];
    const float4 x1 = reinterpret_cast<const float4*>(x)[point * 8 + q * 2 + 1];
    half8 ax;
    ax[0] = (_Float16)x0.x; ax[1] = (_Float16)x0.y;
    ax[2] = (_Float16)x0.z; ax[3] = (_Float16)x0.w;
    ax[4] = (_Float16)x1.x; ax[5] = (_Float16)x1.y;
    ax[6] = (_Float16)x1.z; ax[7] = (_Float16)x1.w;

    half8 b0, b1;
#pragma unroll
    for (int j = 0; j < 8; ++j) {
        b0[j] = (_Float16)W2d[(q * 8 + j) * kD + n];
        b1[j] = (_Float16)W2d[(q * 8 + j) * kD + 16 + n];
    }
    f32x4 a0 = {0.f, 0.f, 0.f, 0.f}, a1 = {0.f, 0.f, 0.f, 0.f};
    a0 = __builtin_amdgcn_mfma_f32_16x16x32_f16(ax, b0, a0, 0, 0, 0);
    a1 = __builtin_amdgcn_mfma_f32_16x16x32_f16(ax, b1, a1, 0, 0, 0);

    const float g20 = g2v[n], g21 = g2v[16 + n];
    const float c20 = b2v[n], c21 = b2v[16 + n];
#pragma unroll
    for (int r = 0; r < 4; ++r) {
        const int pm = pbase + q * 4 + r;      // C/D row m = q*4 + r
        z[pm * 16 + n] = __floats2half2_rn(relu_(fmaf(a0[r], g20, c20)),
                                           relu_(fmaf(a1[r], g21, c21)));
    }
}

// ---------------------------------------------------------------------------
// blk: adjacent-lane gather -> packed fp16 max/sum (native _Float16 vectors;
// result IS the A-frag bit pattern) -> wave-local LDS bounce -> MFMA conv2
// -> wave-local fp32 transpose -> vectorized epilogue -> MFMA z-next ->
// C-native store. XCD-batch swizzle for gather L2 residency.
// MODE: 0=first, 1=mid(+cur), 2=mid, 3=last.
// ---------------------------------------------------------------------------
template <int MODE>
__global__ __launch_bounds__(kThreads, 4)
void blk_kernel(const uint4* __restrict__ zsrc, const uint4* __restrict__ idx16,
                const uint4* __restrict__ wfrag,
                const float* __restrict__ g1v, const float* __restrict__ b1v,
                const float* __restrict__ g2v, const float* __restrict__ b2v,
                const uint4* __restrict__ prev, uint4* __restrict__ cur,
                float* __restrict__ sacc, __half2* __restrict__ znext)
{
    __shared__ __align__(16) _Float16 gmax[4][16][40];   // 5120 B
    __shared__ __align__(16) _Float16 gmean[4][16][40];  // 5120 B
    __shared__ float2 tb[4][16][17];                     // 8704 B

    const int tid  = threadIdx.x;
    const int w    = tid >> 6;
    const int lane = tid & 63;
    const int n    = lane & 15;
    const int q    = lane >> 4;
    const int blockPbase = swizzled_pbase(blockIdx.x);
    const int pbase = blockPbase + w * 16;
    const int point = pbase + n;
    const int base  = pbase & ~(kN - 1);       // batch offset (wave-uniform)

    // ---- gather phase: lane = 4*gpt + gq (adjacent quads per point) ----
    const int gpt = lane >> 2;
    const int gq  = lane & 3;
    const int gpoint = pbase + gpt;
    const uint4 iv0 = idx16[gpoint * 2 + 0];   // 4 lanes same addr -> broadcast
    const uint4 iv1 = idx16[gpoint * 2 + 1];

    // packed fp16 online max/sum (max exact; fp16 sum error ~1e-4 on mean)
    half8 hmx = (half8)(_Float16)0;            // relu output >= 0
    half8 hsm = (half8)(_Float16)0;
#pragma unroll
    for (int k = 0; k < 16; ++k) {
        unsigned word;
        if (k < 8) word = reinterpret_cast<const unsigned*>(&iv0)[k >> 1];
        else       word = reinterpret_cast<const unsigned*>(&iv1)[(k - 8) >> 1];
        const int row = (k & 1) ? (int)(word >> 16) : (int)(word & 0xFFFFu);
        const uint4 u = zsrc[(base + row) * 4 + gq];   // lanes 4p..4p+3: 64 B line
        const half8 hv = *reinterpret_cast<const half8*>(&u);
        hsm += hv;                                     // v_pk_add_f16 x4
#pragma unroll
        for (int c = 0; c < 8; ++c)
            hmx[c] = hmx[c] > hv[c] ? hmx[c] : hv[c];  // v_max_f16
    }
    {
        const half8 hmn = hsm * (_Float16)0.0625;
        *reinterpret_cast<uint4*>(&gmax[w][gpt][gq * 8]) =
            *reinterpret_cast<const uint4*>(&hmx);
        *reinterpret_cast<uint4*>(&gmean[w][gpt][gq * 8]) =
            *reinterpret_cast<const uint4*>(&hmn);
    }
    __builtin_amdgcn_wave_barrier();   // same wave writes & reads; DS wave-ordered

    // ---- A-frag lanes (n = point, q = k-quarter) pick up their fragments
    const half8 amax  = *reinterpret_cast<const half8*>(&gmax[w][n][q * 8]);
    const half8 amean = *reinterpret_cast<const half8*>(&gmean[w][n][q * 8]);

    const uint4 f0 = wfrag[0 * 64 + lane];
    const uint4 f1 = wfrag[1 * 64 + lane];
    const uint4 f2 = wfrag[2 * 64 + lane];
    const uint4 f3 = wfrag[3 * 64 + lane];
    const half8 bA0 = *reinterpret_cast<const half8*>(&f0);
    const half8 bA1 = *reinterpret_cast<const half8*>(&f1);
    const half8 bB0 = *reinterpret_cast<const half8*>(&f2);
    const half8 bB1 = *reinterpret_cast<const half8*>(&f3);

    // ---- conv2 MFMA ----
    f32x4 acc0 = {0.f, 0.f, 0.f, 0.f}, acc1 = {0.f, 0.f, 0.f, 0.f};
    acc0 = __builtin_amdgcn_mfma_f32_16x16x32_f16(amax,  bA0, acc0, 0, 0, 0);
    acc0 = __builtin_amdgcn_mfma_f32_16x16x32_f16(amean, bB0, acc0, 0, 0, 0);
    acc1 = __builtin_amdgcn_mfma_f32_16x16x32_f16(amax,  bA1, acc1, 0, 0, 0);
    acc1 = __builtin_amdgcn_mfma_f32_16x16x32_f16(amean, bB1, acc1, 0, 0, 0);

    const float g10 = g1v[n], g11 = g1v[16 + n];
    const float c10 = b1v[n], c11 = b1v[16 + n];
#pragma unroll
    for (int r = 0; r < 4; ++r) {
        tb[w][q * 4 + r][n] = make_float2(fmaf(acc0[r], g10, c10),
                                          fmaf(acc1[r], g11, c11));
    }
    __builtin_amdgcn_wave_barrier();
    float y8[8];
#pragma unroll
    for (int s = 0; s < 4; ++s) {
        const float2 f = tb[w][n][q * 4 + s];
        y8[2 * s] = f.x; y8[2 * s + 1] = f.y;
    }

    // ---- A-layout epilogue (coalesced 16 B global I/O) ----
    const int sb0 = point * kD + q * 4;
    const int sb1 = sb0 + 16;
    float t8[8];
    if (MODE == 0) {
        reinterpret_cast<float4*>(sacc)[sb0 >> 2] = make_float4(y8[0], y8[2], y8[4], y8[6]);
        reinterpret_cast<float4*>(sacc)[sb1 >> 2] = make_float4(y8[1], y8[3], y8[5], y8[7]);
        half8 ch;
#pragma unroll
        for (int c = 0; c < 8; ++c) ch[c] = (_Float16)y8[c];
        cur[point * 4 + q] = *reinterpret_cast<const uint4*>(&ch);
#pragma unroll
        for (int c = 0; c < 8; ++c) t8[c] = lrelu_(y8[c]);
    } else if (MODE == 1 || MODE == 2) {
        float4 s0 = reinterpret_cast<const float4*>(sacc)[sb0 >> 2];
        float4 s1 = reinterpret_cast<const float4*>(sacc)[sb1 >> 2];
        s0.x += y8[0]; s0.y += y8[2]; s0.z += y8[4]; s0.w += y8[6];
        s1.x += y8[1]; s1.y += y8[3]; s1.z += y8[5]; s1.w += y8[7];
        reinterpret_cast<float4*>(sacc)[sb0 >> 2] = s0;
        reinterpret_cast<float4*>(sacc)[sb1 >> 2] = s1;
        const uint4 pv = prev[point * 4 + q];
        const __half2* ph = reinterpret_cast<const __half2*>(&pv);
#pragma unroll
        for (int c = 0; c < 4; ++c) {
            const float2 f = __half22float2(ph[c]);
            t8[2 * c]     = lrelu_(y8[2 * c] + f.x);
            t8[2 * c + 1] = lrelu_(y8[2 * c + 1] + f.y);
        }
        if (MODE == 1) {
            half8 ch;
#pragma unroll
            for (int c = 0; c < 8; ++c) ch[c] = (_Float16)y8[c];
            cur[point * 4 + q] = *reinterpret_cast<const uint4*>(&ch);
        }
    } else {  // MODE == 3
        const float4 s0 = reinterpret_cast<const float4*>(sacc)[sb0 >> 2];
        const float4 s1 = reinterpret_cast<const float4*>(sacc)[sb1 >> 2];
        reinterpret_cast<float4*>(sacc)[sb0 >> 2] =
            make_float4(lrelu_(s0.x + y8[0]), lrelu_(s0.y + y8[2]),
                        lrelu_(s0.z + y8[4]), lrelu_(s0.w + y8[6]));
        reinterpret_cast<float4*>(sacc)[sb1 >> 2] =
            make_float4(lrelu_(s1.x + y8[1]), lrelu_(s1.y + y8[3]),
                        lrelu_(s1.z + y8[5]), lrelu_(s1.w + y8[7]));
        return;
    }

    // ---- z-next MFMA; C-layout-native store ----
    half8 at;
#pragma unroll
    for (int c = 0; c < 8; ++c) at[c] = (_Float16)t8[c];
    const uint4 f4 = wfrag[4 * 64 + lane];
    const uint4 f5 = wfrag[5 * 64 + lane];
    const half8 bz0 = *reinterpret_cast<const half8*>(&f4);
    const half8 bz1 = *reinterpret_cast<const half8*>(&f5);
    f32x4 az0 = {0.f, 0.f, 0.f, 0.f}, az1 = {0.f, 0.f, 0.f, 0.f};
    az0 = __builtin_amdgcn_mfma_f32_16x16x32_f16(at, bz0, az0, 0, 0, 0);
    az1 = __builtin_amdgcn_mfma_f32_16x16x32_f16(at, bz1, az1, 0, 0, 0);

    const float g20 = g2v[n], g21 = g2v[16 + n];
    const float c20 = b2v[n], c21 = b2v[16 + n];
#pragma unroll
    for (int r = 0; r < 4; ++r) {
        const int pm = pbase + q * 4 + r;
        znext[pm * 16 + n] = __floats2half2_rn(relu_(fmaf(az0[r], g20, c20)),
                                               relu_(fmaf(az1[r], g21, c21)));
    }
}

}  // namespace

extern "C" void kernel_launch(void* const* d_in, const int* in_sizes, int n_in,
                              void* d_out, int out_size, void* d_ws, size_t ws_size,
                              hipStream_t stream)
{
    const float* x   = (const float*)d_in[0];
    const int4*  idx = (const int4*)d_in[1];
    const float* W2d = (const float*)d_in[2];
    const float* g2  = (const float*)d_in[3];
    const float* b2  = (const float*)d_in[4];
    const float* W1d = (const float*)d_in[5];
    const float* g1  = (const float*)d_in[6];
    const float* b1  = (const float*)d_in[7];
    float* out = (float*)d_out;     // doubles as sacc between dispatches
    char*  ws  = (char*)d_ws;

    constexpr size_t kHalfMap = (size_t)kPts * kD * sizeof(__half);  // 8 MB
    __half2* zA = (__half2*)(ws);
    __half2* zB = (__half2*)(ws + kHalfMap);
    uint4*   cA = (uint4*)(ws + 2 * kHalfMap);                 // x1 (fp16, pi order)
    uint4*   cB = (uint4*)(ws + 3 * kHalfMap);                 // x2 (fp16, pi order)
    uint2*   idx16 = (uint2*)(ws + 4 * kHalfMap);              // 4 MB
    uint4*   wpack = (uint4*)(ws + 4 * kHalfMap + (size_t)kPts * 32);  // 24 KB

    const dim3 grid(kBlocks), blk(kThreads);
    zprep_kernel<<<grid, blk, 0, stream>>>(x, idx, W2d, W1d, g2, b2,
                                           zA, idx16, wpack);

    const uint4* i16 = (const uint4*)idx16;
    blk_kernel<0><<<grid, blk, 0, stream>>>((const uint4*)zA, i16,
        wpack + (2 + 0 * 6) * 64, g1, b1, g2 + 1 * kD, b2 + 1 * kD,
        nullptr, cA, out, zB);
    blk_kernel<1><<<grid, blk, 0, stream>>>((const uint4*)zB, i16,
        wpack + (2 + 1 * 6) * 64, g1 + 1 * kD, b1 + 1 * kD, g2 + 2 * kD, b2 + 2 * kD,
        cA, cB, out, zA);
    blk_kernel<2><<<grid, blk, 0, stream>>>((const uint4*)zA, i16,
        wpack + (2 + 2 * 6) * 64, g1 + 2 * kD, b1 + 2 * kD, g2 + 3 * kD, b2 + 3 * kD,
        cB, nullptr, out, zB);
    blk_kernel<3><<<grid, blk, 0, stream>>>((const uint4*)zB, i16,
        wpack + (2 + 3 * 6) * 64, g1 + 3 * kD, b1 + 3 * kD, nullptr, nullptr,
        nullptr, nullptr, out, nullptr);
}

// Round 15
// 171.755 us; speedup vs baseline: 1.1462x; 1.0094x over previous
//
#include <hip/hip_runtime.h>
#include <hip/hip_fp16.h>

namespace {

typedef _Float16 half8 __attribute__((ext_vector_type(8)));
typedef float f32x4 __attribute__((ext_vector_type(4)));

constexpr int kN = 65536;
constexpr int kD = 32;
constexpr int kPts = 2 * kN;                 // 131072 points (B*N)
constexpr int kThreads = 256;                // 4 waves
constexpr int kPtsPerBlk = 64;               // 16 points per wave
constexpr int kBlocks = kPts / kPtsPerBlk;   // 2048
constexpr int kNumFrags = 24;
static_assert(kBlocks * kPtsPerBlk == kPts, "grid must tile points exactly");
static_assert(kN % kPtsPerBlk == 0, "blocks must not straddle batch boundary");

__device__ __forceinline__ float relu_(float v) { return fmaxf(v, 0.f); }
__device__ __forceinline__ float lrelu_(float v) { return v >= 0.f ? v : 0.2f * v; }

// channel permutation induced by the interleaved z-row layout:
// row = 16 half2 slots, slot n holds (ch n, ch n+16).
__device__ __forceinline__ int pi_(int k) {
    const int c = ((k >> 3) << 2) + ((k & 7) >> 1);
    return (k & 1) ? c + 16 : c;
}

// XCD-aware block swizzle: XCDs 0-3 -> batch 0, XCDs 4-7 -> batch 1
// (per-XCD gather set == 4 MB L2 capacity). [measured R12: -4 us]
__device__ __forceinline__ int swizzled_pbase(int bid) {
    const int xcd   = bid & 7;
    const int slot  = bid >> 3;                           // 0..255
    const int batch = xcd >> 2;
    const int local = (xcd & 3) * (kBlocks / 8) + slot;   // 0..1023
    return batch * kN + local * kPtsPerBlk;
}

// ---------------------------------------------------------------------------
// zprep: z1 = relu((x @ W2_0) * g2_0 + b2_0) (interleaved fp16), packs idx
// to u16 pairs, and (block 0 only) builds the fp16 B-fragment bank.
// ---------------------------------------------------------------------------
__global__ __launch_bounds__(kThreads, 4)
void zprep_kernel(const float* __restrict__ x, const int4* __restrict__ idx4,
                  const float* __restrict__ W2d, const float* __restrict__ W1d,
                  const float* __restrict__ g2v, const float* __restrict__ b2v,
                  __half2* __restrict__ z, uint2* __restrict__ idx16,
                  uint4* __restrict__ wpack)
{
    const int tid = threadIdx.x;
    if (blockIdx.x == 0) {
        for (int id = tid; id < kNumFrags * 64; id += kThreads) {
            const int fid = id >> 6, l = id & 63, n = l & 15, q = l >> 4;
            half8 v;
            if (fid < 2) {
                const int h = fid;
#pragma unroll
                for (int j = 0; j < 8; ++j)
                    v[j] = (_Float16)W2d[(q * 8 + j) * kD + h * 16 + n];
            } else {
                const int rel = fid - 2;
                const int layer = (rel < 18) ? rel / 6 : 3;
                const int sub   = (rel < 18) ? rel % 6 : rel - 18;
                if (sub < 4) {
                    const int p = sub >> 1, h = sub & 1;
#pragma unroll
                    for (int j = 0; j < 8; ++j)
                        v[j] = (_Float16)W1d[layer * 2048 + (p * 32 + pi_(q * 8 + j)) * kD + h * 16 + n];
                } else {
                    const int h = sub - 4;
#pragma unroll
                    for (int j = 0; j < 8; ++j)
                        v[j] = (_Float16)W2d[(layer + 1) * 1024 + pi_(q * 8 + j) * kD + h * 16 + n];
                }
            }
            wpack[id] = *reinterpret_cast<const uint4*>(&v);
        }
    }
    {
        const int p = blockIdx.x * kPtsPerBlk + (tid >> 2);
        const int part = tid & 3;
        const int4 iv = idx4[p * 4 + part];
        uint2 o;
        o.x = (unsigned)(iv.x & 0xFFFF) | ((unsigned)iv.y << 16);
        o.y = (unsigned)(iv.z & 0xFFFF) | ((unsigned)iv.w << 16);
        idx16[p * 4 + part] = o;
    }
    const int w    = tid >> 6;
    const int lane = tid & 63;
    const int n    = lane & 15;
    const int q    = lane >> 4;
    const int pbase = blockIdx.x * kPtsPerBlk + w * 16;
    const int point = pbase + n;

    const float4 x0 = reinterpret_cast<const float4*>(x)[point * 8 + q * 2];
    const float4 x1 = reinterpret_cast<const float4*>(x)[point * 8 + q * 2 + 1];
    half8 ax;
    ax[0] = (_Float16)x0.x; ax[1] = (_Float16)x0.y;
    ax[2] = (_Float16)x0.z; ax[3] = (_Float16)x0.w;
    ax[4] = (_Float16)x1.x; ax[5] = (_Float16)x1.y;
    ax[6] = (_Float16)x1.z; ax[7] = (_Float16)x1.w;

    half8 b0, b1;
#pragma unroll
    for (int j = 0; j < 8; ++j) {
        b0[j] = (_Float16)W2d[(q * 8 + j) * kD + n];
        b1[j] = (_Float16)W2d[(q * 8 + j) * kD + 16 + n];
    }
    f32x4 a0 = {0.f, 0.f, 0.f, 0.f}, a1 = {0.f, 0.f, 0.f, 0.f};
    a0 = __builtin_amdgcn_mfma_f32_16x16x32_f16(ax, b0, a0, 0, 0, 0);
    a1 = __builtin_amdgcn_mfma_f32_16x16x32_f16(ax, b1, a1, 0, 0, 0);

    const float g20 = g2v[n], g21 = g2v[16 + n];
    const float c20 = b2v[n], c21 = b2v[16 + n];
#pragma unroll
    for (int r = 0; r < 4; ++r) {
        const int pm = pbase + q * 4 + r;      // C/D row m = q*4 + r
        z[pm * 16 + n] = __floats2half2_rn(relu_(fmaf(a0[r], g20, c20)),
                                           relu_(fmaf(a1[r], g21, c21)));
    }
}

// ---------------------------------------------------------------------------
// blk: adjacent-lane gather with TWO-PHASE load-then-reduce (all 16 gather
// loads in flight simultaneously -> max per-lane MLP) -> packed fp16
// max/sum -> wave-local LDS bounce -> MFMA conv2 -> wave-local fp32
// transpose -> vectorized epilogue (sacc/prev hoisted before the gather) ->
// MFMA z-next -> C-native store. XCD-batch swizzle.
// MODE: 0=first, 1=mid(+cur), 2=mid, 3=last.
// ---------------------------------------------------------------------------
template <int MODE>
__global__ __launch_bounds__(kThreads, 4)
void blk_kernel(const uint4* __restrict__ zsrc, const uint4* __restrict__ idx16,
                const uint4* __restrict__ wfrag,
                const float* __restrict__ g1v, const float* __restrict__ b1v,
                const float* __restrict__ g2v, const float* __restrict__ b2v,
                const uint4* __restrict__ prev, uint4* __restrict__ cur,
                float* __restrict__ sacc, __half2* __restrict__ znext)
{
    __shared__ __align__(16) _Float16 gmax[4][16][40];   // 5120 B
    __shared__ __align__(16) _Float16 gmean[4][16][40];  // 5120 B
    __shared__ float2 tb[4][16][17];                     // 8704 B

    const int tid  = threadIdx.x;
    const int w    = tid >> 6;
    const int lane = tid & 63;
    const int n    = lane & 15;
    const int q    = lane >> 4;
    const int blockPbase = swizzled_pbase(blockIdx.x);
    const int pbase = blockPbase + w * 16;
    const int point = pbase + n;
    const int base  = pbase & ~(kN - 1);       // batch offset (wave-uniform)

    // ---- hoisted independent epilogue loads (hide under the gather) ----
    const int sb0 = point * kD + q * 4;
    const int sb1 = sb0 + 16;
    float4 sv0, sv1; uint4 pv;
    if (MODE != 0) {
        sv0 = reinterpret_cast<const float4*>(sacc)[sb0 >> 2];
        sv1 = reinterpret_cast<const float4*>(sacc)[sb1 >> 2];
    }
    if (MODE == 1 || MODE == 2) pv = prev[point * 4 + q];

    // ---- gather phase: lane = 4*gpt + gq (adjacent quads per point) ----
    const int gpt = lane >> 2;
    const int gq  = lane & 3;
    const int gpoint = pbase + gpt;
    const uint4 iv0 = idx16[gpoint * 2 + 0];   // 4 lanes same addr -> broadcast
    const uint4 iv1 = idx16[gpoint * 2 + 1];

    // phase 1: issue ALL 16 loads (live in gbuf -> back-to-back issue)
    uint4 gbuf[16];
#pragma unroll
    for (int k = 0; k < 16; ++k) {
        unsigned word;
        if (k < 8) word = reinterpret_cast<const unsigned*>(&iv0)[k >> 1];
        else       word = reinterpret_cast<const unsigned*>(&iv1)[(k - 8) >> 1];
        const int row = (k & 1) ? (int)(word >> 16) : (int)(word & 0xFFFFu);
        gbuf[k] = zsrc[(base + row) * 4 + gq];  // lanes 4p..4p+3: one 64 B line
    }
    // phase 2: packed fp16 reduce (consumption of k overlaps loads k+1..15)
    half8 hmx = (half8)(_Float16)0;            // relu output >= 0
    half8 hsm = (half8)(_Float16)0;
#pragma unroll
    for (int k = 0; k < 16; ++k) {
        const half8 hv = *reinterpret_cast<const half8*>(&gbuf[k]);
        hsm += hv;                                     // v_pk_add_f16 x4
#pragma unroll
        for (int c = 0; c < 8; ++c)
            hmx[c] = hmx[c] > hv[c] ? hmx[c] : hv[c];  // v_max_f16
    }
    {
        const half8 hmn = hsm * (_Float16)0.0625;
        *reinterpret_cast<uint4*>(&gmax[w][gpt][gq * 8]) =
            *reinterpret_cast<const uint4*>(&hmx);
        *reinterpret_cast<uint4*>(&gmean[w][gpt][gq * 8]) =
            *reinterpret_cast<const uint4*>(&hmn);
    }
    __builtin_amdgcn_wave_barrier();   // same wave writes & reads; DS wave-ordered

    // ---- A-frag lanes (n = point, q = k-quarter) pick up their fragments
    const half8 amax  = *reinterpret_cast<const half8*>(&gmax[w][n][q * 8]);
    const half8 amean = *reinterpret_cast<const half8*>(&gmean[w][n][q * 8]);

    const uint4 f0 = wfrag[0 * 64 + lane];
    const uint4 f1 = wfrag[1 * 64 + lane];
    const uint4 f2 = wfrag[2 * 64 + lane];
    const uint4 f3 = wfrag[3 * 64 + lane];
    const half8 bA0 = *reinterpret_cast<const half8*>(&f0);
    const half8 bA1 = *reinterpret_cast<const half8*>(&f1);
    const half8 bB0 = *reinterpret_cast<const half8*>(&f2);
    const half8 bB1 = *reinterpret_cast<const half8*>(&f3);

    // ---- conv2 MFMA ----
    f32x4 acc0 = {0.f, 0.f, 0.f, 0.f}, acc1 = {0.f, 0.f, 0.f, 0.f};
    acc0 = __builtin_amdgcn_mfma_f32_16x16x32_f16(amax,  bA0, acc0, 0, 0, 0);
    acc0 = __builtin_amdgcn_mfma_f32_16x16x32_f16(amean, bB0, acc0, 0, 0, 0);
    acc1 = __builtin_amdgcn_mfma_f32_16x16x32_f16(amax,  bA1, acc1, 0, 0, 0);
    acc1 = __builtin_amdgcn_mfma_f32_16x16x32_f16(amean, bB1, acc1, 0, 0, 0);

    const float g10 = g1v[n], g11 = g1v[16 + n];
    const float c10 = b1v[n], c11 = b1v[16 + n];
#pragma unroll
    for (int r = 0; r < 4; ++r) {
        tb[w][q * 4 + r][n] = make_float2(fmaf(acc0[r], g10, c10),
                                          fmaf(acc1[r], g11, c11));
    }
    __builtin_amdgcn_wave_barrier();
    float y8[8];
#pragma unroll
    for (int s = 0; s < 4; ++s) {
        const float2 f = tb[w][n][q * 4 + s];
        y8[2 * s] = f.x; y8[2 * s + 1] = f.y;
    }

    // ---- A-layout epilogue (coalesced 16 B global I/O) ----
    float t8[8];
    if (MODE == 0) {
        reinterpret_cast<float4*>(sacc)[sb0 >> 2] = make_float4(y8[0], y8[2], y8[4], y8[6]);
        reinterpret_cast<float4*>(sacc)[sb1 >> 2] = make_float4(y8[1], y8[3], y8[5], y8[7]);
        half8 ch;
#pragma unroll
        for (int c = 0; c < 8; ++c) ch[c] = (_Float16)y8[c];
        cur[point * 4 + q] = *reinterpret_cast<const uint4*>(&ch);
#pragma unroll
        for (int c = 0; c < 8; ++c) t8[c] = lrelu_(y8[c]);
    } else if (MODE == 1 || MODE == 2) {
        sv0.x += y8[0]; sv0.y += y8[2]; sv0.z += y8[4]; sv0.w += y8[6];
        sv1.x += y8[1]; sv1.y += y8[3]; sv1.z += y8[5]; sv1.w += y8[7];
        reinterpret_cast<float4*>(sacc)[sb0 >> 2] = sv0;
        reinterpret_cast<float4*>(sacc)[sb1 >> 2] = sv1;
        const __half2* ph = reinterpret_cast<const __half2*>(&pv);
#pragma unroll
        for (int c = 0; c < 4; ++c) {
            const float2 f = __half22float2(ph[c]);
            t8[2 * c]     = lrelu_(y8[2 * c] + f.x);
            t8[2 * c + 1] = lrelu_(y8[2 * c + 1] + f.y);
        }
        if (MODE == 1) {
            half8 ch;
#pragma unroll
            for (int c = 0; c < 8; ++c) ch[c] = (_Float16)y8[c];
            cur[point * 4 + q] = *reinterpret_cast<const uint4*>(&ch);
        }
    } else {  // MODE == 3
        reinterpret_cast<float4*>(sacc)[sb0 >> 2] =
            make_float4(lrelu_(sv0.x + y8[0]), lrelu_(sv0.y + y8[2]),
                        lrelu_(sv0.z + y8[4]), lrelu_(sv0.w + y8[6]));
        reinterpret_cast<float4*>(sacc)[sb1 >> 2] =
            make_float4(lrelu_(sv1.x + y8[1]), lrelu_(sv1.y + y8[3]),
                        lrelu_(sv1.z + y8[5]), lrelu_(sv1.w + y8[7]));
        return;
    }

    // ---- z-next MFMA; C-layout-native store ----
    half8 at;
#pragma unroll
    for (int c = 0; c < 8; ++c) at[c] = (_Float16)t8[c];
    const uint4 f4 = wfrag[4 * 64 + lane];
    const uint4 f5 = wfrag[5 * 64 + lane];
    const half8 bz0 = *reinterpret_cast<const half8*>(&f4);
    const half8 bz1 = *reinterpret_cast<const half8*>(&f5);
    f32x4 az0 = {0.f, 0.f, 0.f, 0.f}, az1 = {0.f, 0.f, 0.f, 0.f};
    az0 = __builtin_amdgcn_mfma_f32_16x16x32_f16(at, bz0, az0, 0, 0, 0);
    az1 = __builtin_amdgcn_mfma_f32_16x16x32_f16(at, bz1, az1, 0, 0, 0);

    const float g20 = g2v[n], g21 = g2v[16 + n];
    const float c20 = b2v[n], c21 = b2v[16 + n];
#pragma unroll
    for (int r = 0; r < 4; ++r) {
        const int pm = pbase + q * 4 + r;
        znext[pm * 16 + n] = __floats2half2_rn(relu_(fmaf(az0[r], g20, c20)),
                                               relu_(fmaf(az1[r], g21, c21)));
    }
}

}  // namespace

extern "C" void kernel_launch(void* const* d_in, const int* in_sizes, int n_in,
                              void* d_out, int out_size, void* d_ws, size_t ws_size,
                              hipStream_t stream)
{
    const float* x   = (const float*)d_in[0];
    const int4*  idx = (const int4*)d_in[1];
    const float* W2d = (const float*)d_in[2];
    const float* g2  = (const float*)d_in[3];
    const float* b2  = (const float*)d_in[4];
    const float* W1d = (const float*)d_in[5];
    const float* g1  = (const float*)d_in[6];
    const float* b1  = (const float*)d_in[7];
    float* out = (float*)d_out;     // doubles as sacc between dispatches
    char*  ws  = (char*)d_ws;

    constexpr size_t kHalfMap = (size_t)kPts * kD * sizeof(__half);  // 8 MB
    __half2* zA = (__half2*)(ws);
    __half2* zB = (__half2*)(ws + kHalfMap);
    uint4*   cA = (uint4*)(ws + 2 * kHalfMap);                 // x1 (fp16, pi order)
    uint4*   cB = (uint4*)(ws + 3 * kHalfMap);                 // x2 (fp16, pi order)
    uint2*   idx16 = (uint2*)(ws + 4 * kHalfMap);              // 4 MB
    uint4*   wpack = (uint4*)(ws + 4 * kHalfMap + (size_t)kPts * 32);  // 24 KB

    const dim3 grid(kBlocks), blk(kThreads);
    zprep_kernel<<<grid, blk, 0, stream>>>(x, idx, W2d, W1d, g2, b2,
                                           zA, idx16, wpack);

    const uint4* i16 = (const uint4*)idx16;
    blk_kernel<0><<<grid, blk, 0, stream>>>((const uint4*)zA, i16,
        wpack + (2 + 0 * 6) * 64, g1, b1, g2 + 1 * kD, b2 + 1 * kD,
        nullptr, cA, out, zB);
    blk_kernel<1><<<grid, blk, 0, stream>>>((const uint4*)zB, i16,
        wpack + (2 + 1 * 6) * 64, g1 + 1 * kD, b1 + 1 * kD, g2 + 2 * kD, b2 + 2 * kD,
        cA, cB, out, zA);
    blk_kernel<2><<<grid, blk, 0, stream>>>((const uint4*)zA, i16,
        wpack + (2 + 2 * 6) * 64, g1 + 2 * kD, b1 + 2 * kD, g2 + 3 * kD, b2 + 3 * kD,
        cB, nullptr, out, zB);
    blk_kernel<3><<<grid, blk, 0, stream>>>((const uint4*)zB, i16,
        wpack + (2 + 3 * 6) * 64, g1 + 3 * kD, b1 + 3 * kD, nullptr, nullptr,
        nullptr, nullptr, out, nullptr);
}